// Round 21
// baseline (578.000 us; speedup 1.0000x reference)
//
#include <hip/hip_runtime.h>
#include <hip/hip_bf16.h>

#define NDIM 256
#define FDIM 32
#define HOPS 4

typedef __attribute__((ext_vector_type(8))) short short8;
typedef __attribute__((ext_vector_type(4))) float f32x4;
typedef __attribute__((ext_vector_type(2))) float f32x2;

// ---------- helpers ----------
__device__ inline float b2f(unsigned short u) {
    union { unsigned int i; float f; } v; v.i = ((unsigned int)u) << 16; return v.f;
}
__device__ inline unsigned short f2b(float f) {
    union { float f; unsigned int i; } v; v.f = f;
    unsigned int r = v.i + 0x7FFF + ((v.i >> 16) & 1);
    return (unsigned short)(r >> 16);
}
__device__ inline unsigned char f2fp8(float v) {
    return (unsigned char)(__builtin_amdgcn_cvt_pk_fp8_f32(v, v, 0, false) & 0xFF);
}

// ---------- CSR build ----------
__global__ void hist_kernel(const int* __restrict__ dst, int* __restrict__ deg, int E) {
    int e = blockIdx.x * blockDim.x + threadIdx.x;
    if (e < E) atomicAdd(&deg[dst[e]], 1);
}

__global__ __launch_bounds__(1024) void scan_kernel(const int* __restrict__ deg,
                                                    int* __restrict__ rowptr,
                                                    int* __restrict__ cursor, int n) {
    __shared__ int wsum[16];
    int t = threadIdx.x;
    int per4 = (n + 4095) >> 12;
    int base = t * per4 * 4;
    int4 v4[8];
#pragma unroll 8
    for (int j = 0; j < per4; ++j) {
        int4 d = *(const int4*)(deg + base + j * 4);
        d.x = (d.x + 7) & ~7; d.y = (d.y + 7) & ~7;
        d.z = (d.z + 7) & ~7; d.w = (d.w + 7) & ~7;
        v4[j] = d;
    }
    int s = 0;
#pragma unroll 8
    for (int j = 0; j < per4; ++j) s += v4[j].x + v4[j].y + v4[j].z + v4[j].w;

    int lane = t & 63, wid = t >> 6;
    int v = s;
#pragma unroll
    for (int d = 1; d < 64; d <<= 1) {
        int u = __shfl_up(v, d, 64);
        if (lane >= d) v += u;
    }
    if (lane == 63) wsum[wid] = v;
    __syncthreads();
    if (wid == 0) {
        int ws = (lane < 16) ? wsum[lane] : 0;
#pragma unroll
        for (int d = 1; d < 16; d <<= 1) {
            int u = __shfl_up(ws, d, 64);
            if (lane >= d) ws += u;
        }
        if (lane < 16) wsum[lane] = ws;
    }
    __syncthreads();
    int run = (wid > 0 ? wsum[wid - 1] : 0) + (v - s);
#pragma unroll 8
    for (int j = 0; j < per4; ++j) {
        int idx = base + j * 4;
        int4 o;
        o.x = run; run += v4[j].x;
        o.y = run; run += v4[j].y;
        o.z = run; run += v4[j].z;
        o.w = run; run += v4[j].w;
        if (idx + 3 < n) {
            *(int4*)(rowptr + idx) = o;
            *(int4*)(cursor + idx) = o;
        } else if (idx < n) {
            const int* op = (const int*)&o;
            for (int e = 0; e < 4 && idx + e < n; ++e) {
                rowptr[idx + e] = op[e];
                cursor[idx + e] = op[e];
            }
        }
    }
    if (t == 1023) rowptr[n] = run;
}

__global__ void fill_kernel(const int* __restrict__ src, const int* __restrict__ dst,
                            int* __restrict__ cursor, int* __restrict__ col, int E) {
    int e = blockIdx.x * blockDim.x + threadIdx.x;
    if (e < E) {
        int d = dst[e];
        int p = atomicAdd(&cursor[d], 1);
        col[p] = src[e];
    }
}

__global__ void pad_kernel(const int* __restrict__ rowptr, const int* __restrict__ deg,
                           int* __restrict__ col, int n) {
    int v = blockIdx.x * blockDim.x + threadIdx.x;
    if (v < n) {
        int s = rowptr[v] + deg[v];
        int e = rowptr[v + 1];
        for (int i = s; i < e; ++i) col[i] = n;
    }
}

// ---------- merged weight prep ----------
__global__ __launch_bounds__(256) void wprep_kernel(const float* __restrict__ Wm,
                                                    const float* __restrict__ Wu,
                                                    const float* __restrict__ bm,
                                                    unsigned short* __restrict__ WtA,
                                                    unsigned short* __restrict__ WtB,
                                                    unsigned short* __restrict__ WtC,
                                                    float* __restrict__ cvec,
                                                    int* __restrict__ geInt,
                                                    unsigned char* __restrict__ h8row) {
    __shared__ float T[32][33];
    __shared__ float Af[32][68];
    __shared__ float Bf[32][68];
    __shared__ float sb[256];
    int b = blockIdx.x;
    int t = threadIdx.x;

    if (b < 256) {
        int hop = b >> 6;
        int rem = b & 63;
        int k0 = (rem & 7) * 32, n0 = (rem >> 3) * 32;
        const float* src = Wu + (size_t)hop * 512 * 256;
        unsigned short* dstp = WtB + (size_t)hop * 256 * 256;
        int tr = t >> 5, tc = t & 31;
#pragma unroll
        for (int r = 0; r < 4; ++r) {
            int k = tr + r * 8;
            T[tc][k] = src[(size_t)(k0 + k) * 256 + n0 + tc];
        }
        __syncthreads();
#pragma unroll
        for (int r = 0; r < 4; ++r) {
            int nn = tr + r * 8;
            dstp[(size_t)(n0 + nn) * 256 + k0 + tc] = f2b(T[nn][tc]);
        }
    } else if (b < 384) {
        int idx = b - 256;
        int m = idx >> 4;
        int rem = idx & 15;
        int k0 = (rem & 3) * 64, n0 = (rem >> 2) * 64;
        int hop = m >> 1, which = m & 1;
        const float* A = Wm + (size_t)hop * 512 * 256 + (size_t)which * 256 * 256;
        const float* B = Wu + (size_t)hop * 512 * 256 + (size_t)256 * 256;
        unsigned short* W = (which ? WtC : WtA) + (size_t)hop * 256 * 256;
        int tx = t & 15, ty = t >> 4;
        float acc[4][4];
#pragma unroll
        for (int a = 0; a < 4; ++a)
#pragma unroll
            for (int c = 0; c < 4; ++c) acc[a][c] = 0.f;

        for (int j0 = 0; j0 < 256; j0 += 32) {
            __syncthreads();
#pragma unroll
            for (int c = 0; c < 2; ++c) {
                int idx2 = t + c * 256;
                int kk = idx2 >> 3;
                int jj = (idx2 & 7) * 4;
                float4 va = *(const float4*)&A[(size_t)(k0 + kk) * 256 + j0 + jj];
                Af[jj + 0][kk] = va.x; Af[jj + 1][kk] = va.y;
                Af[jj + 2][kk] = va.z; Af[jj + 3][kk] = va.w;
                int jj2 = idx2 >> 4;
                int nn = (idx2 & 15) * 4;
                float4 vb = *(const float4*)&B[(size_t)(j0 + jj2) * 256 + n0 + nn];
                *(float4*)&Bf[jj2][nn] = vb;
            }
            __syncthreads();
#pragma unroll
            for (int jj = 0; jj < 32; ++jj) {
                float av[4];
#pragma unroll
                for (int a = 0; a < 4; ++a) av[a] = Af[jj][ty * 4 + a];
                float4 bv = *(const float4*)&Bf[jj][tx * 4];
#pragma unroll
                for (int a = 0; a < 4; ++a) {
                    acc[a][0] += av[a] * bv.x; acc[a][1] += av[a] * bv.y;
                    acc[a][2] += av[a] * bv.z; acc[a][3] += av[a] * bv.w;
                }
            }
        }
#pragma unroll
        for (int c = 0; c < 4; ++c) {
            int nn = n0 + tx * 4 + c;
            ushort4 o;
            o.x = f2b(acc[0][c]); o.y = f2b(acc[1][c]);
            o.z = f2b(acc[2][c]); o.w = f2b(acc[3][c]);
            *(ushort4*)&W[(size_t)nn * 256 + k0 + ty * 4] = o;
        }
    } else if (b < 388) {
        int hop = b - 384;
        sb[t] = bm[hop * 256 + t];
        __syncthreads();
        const float* B = Wu + (size_t)hop * 512 * 256 + (size_t)256 * 256;
        float acc = 0.f;
#pragma unroll 8
        for (int j = 0; j < 256; ++j) acc += sb[j] * B[(size_t)j * 256 + t];
        cvec[hop * 256 + t] = acc;
    } else {
        geInt[t] = 0;
        h8row[t] = 0;
    }
}

// ---------- initial projection ----------
__global__ void init_h_kernel(const float* __restrict__ nodes,
                              const int* __restrict__ node_types,
                              const float* __restrict__ type_emb,
                              const float* __restrict__ W_proj,
                              const float* __restrict__ b_proj,
                              unsigned short* __restrict__ h,
                              unsigned char* __restrict__ h8, int n) {
    int v = blockIdx.x;
    int t = threadIdx.x;
    __shared__ float sn[FDIM];
    if (t < FDIM) sn[t] = nodes[v * FDIM + t];
    __syncthreads();
    int ty = node_types[v];
    float acc = b_proj[t] + type_emb[ty * NDIM + t];
#pragma unroll
    for (int k = 0; k < FDIM; ++k) acc += sn[k] * W_proj[k * NDIM + t];
    h[(size_t)v * NDIM + t] = f2b(acc);
    h8[(size_t)v * NDIM + t] = f2fp8(acc);
}

// ---------- neighbor sum: fp8 gather, fp32 acc, bf16 out ----------
__global__ __launch_bounds__(256) void agg_kernel(const unsigned char* __restrict__ h8,
                                                  const int* __restrict__ rowptr,
                                                  const int* __restrict__ col,
                                                  unsigned short* __restrict__ S, int n) {
    int wave = threadIdx.x >> 6;
    int lane = threadIdx.x & 63;
    int half = lane >> 5;
    int hl = lane & 31;
    int v = blockIdx.x * 8 + wave * 2 + half;
    if (v >= n) return;
    int beg = rowptr[v], end = rowptr[v + 1];
    float a[8];
#pragma unroll
    for (int e = 0; e < 8; ++e) a[e] = 0.f;
    int cofs = hl * 8;
    for (int i = beg; i < end; i += 8) {
        int cc[8];
#pragma unroll
        for (int j = 0; j < 8; ++j) cc[j] = col[i + j];
        uint2 x[8];
#pragma unroll
        for (int j = 0; j < 8; ++j)
            x[j] = *(const uint2*)(h8 + (size_t)cc[j] * NDIM + cofs);
#pragma unroll
        for (int j = 0; j < 8; ++j) {
            f32x2 p0 = __builtin_amdgcn_cvt_pk_f32_fp8(x[j].x, false);
            f32x2 p1 = __builtin_amdgcn_cvt_pk_f32_fp8(x[j].x, true);
            f32x2 p2 = __builtin_amdgcn_cvt_pk_f32_fp8(x[j].y, false);
            f32x2 p3 = __builtin_amdgcn_cvt_pk_f32_fp8(x[j].y, true);
            a[0] += p0[0]; a[1] += p0[1]; a[2] += p1[0]; a[3] += p1[1];
            a[4] += p2[0]; a[5] += p2[1]; a[6] += p3[0]; a[7] += p3[1];
        }
    }
    uint4 o;
    unsigned short* op = (unsigned short*)&o;
#pragma unroll
    for (int e = 0; e < 8; ++e) op[e] = f2b(a[e]);
    *(uint4*)&S[(size_t)v * NDIM + cofs] = o;
}

// ---------- fused hop GEMM with register-prefetch pipelining ----------
#define BM 128
#define BN 64
#define BK 64
#define ASTR (BK + 8)

template <bool LAST>
__global__ __launch_bounds__(256) void gemm_hop_kernel(const unsigned short* __restrict__ S,
                                                       const unsigned short* __restrict__ hcur,
                                                       const int* __restrict__ deg,
                                                       const unsigned short* __restrict__ WtA,
                                                       const unsigned short* __restrict__ WtB,
                                                       const unsigned short* __restrict__ WtC,
                                                       const float* __restrict__ bupd,
                                                       const float* __restrict__ cvec,
                                                       unsigned short* __restrict__ Out,
                                                       unsigned char* __restrict__ Out8,
                                                       int* __restrict__ geInt, int n) {
    __shared__ unsigned short As[BM][ASTR];
    __shared__ unsigned short Bs[BN][ASTR];
    __shared__ unsigned short Cs[BN][ASTR];
    __shared__ int smax[BN];
    int t = threadIdx.x;
    int lane = t & 63;
    int w = t >> 6;
    int wm = w >> 1, wn = w & 1;
    int quad = lane >> 4, l16 = lane & 15;
    int row0 = blockIdx.x * BM;
    int n0 = blockIdx.y * BN;

    if (LAST) {
        if (t < BN) smax[t] = 0;
    }

    // per-thread staging coordinates
    int rA[4], koA[4];
#pragma unroll
    for (int h2 = 0; h2 < 4; ++h2) {
        int c = t + h2 * 256;
        rA[h2] = c >> 3;
        koA[h2] = (c & 7) * 8;
    }
    int rB[2], koB[2];
#pragma unroll
    for (int h2 = 0; h2 < 2; ++h2) {
        int c = t + h2 * 256;
        rB[h2] = c >> 3;
        koB[h2] = (c & 7) * 8;
    }
    int growA[4];
#pragma unroll
    for (int h2 = 0; h2 < 4; ++h2) {
        int g = row0 + rA[h2];
        growA[h2] = (g >= n) ? (n - 1) : g;
    }

    f32x4 acc1[4][2], acc2[4][2];
#pragma unroll
    for (int i = 0; i < 4; ++i)
#pragma unroll
        for (int j = 0; j < 2; ++j) { acc1[i][j] = (f32x4)(0.f); acc2[i][j] = (f32x4)(0.f); }

    uint4 pA[4], pB[2], pC[2];

    // ===== phase 1: acc1 += S @ M1^T, prefetch-pipelined =====
#pragma unroll
    for (int h2 = 0; h2 < 4; ++h2)
        pA[h2] = *(const uint4*)(S + (size_t)growA[h2] * NDIM + koA[h2]);
#pragma unroll
    for (int h2 = 0; h2 < 2; ++h2)
        pB[h2] = *(const uint4*)(WtA + (size_t)(n0 + rB[h2]) * NDIM + koB[h2]);

    for (int k0 = 0; k0 < NDIM; k0 += BK) {
        __syncthreads();
#pragma unroll
        for (int h2 = 0; h2 < 4; ++h2) *(uint4*)&As[rA[h2]][koA[h2]] = pA[h2];
#pragma unroll
        for (int h2 = 0; h2 < 2; ++h2) *(uint4*)&Bs[rB[h2]][koB[h2]] = pB[h2];
        __syncthreads();
        int k1 = k0 + BK;
        if (k1 < NDIM) {
#pragma unroll
            for (int h2 = 0; h2 < 4; ++h2)
                pA[h2] = *(const uint4*)(S + (size_t)growA[h2] * NDIM + k1 + koA[h2]);
#pragma unroll
            for (int h2 = 0; h2 < 2; ++h2)
                pB[h2] = *(const uint4*)(WtA + (size_t)(n0 + rB[h2]) * NDIM + k1 + koB[h2]);
        } else {
            // preload phase-2 first tile
#pragma unroll
            for (int h2 = 0; h2 < 4; ++h2)
                pA[h2] = *(const uint4*)(hcur + (size_t)growA[h2] * NDIM + koA[h2]);
#pragma unroll
            for (int h2 = 0; h2 < 2; ++h2) {
                size_t widx = (size_t)(n0 + rB[h2]) * NDIM + koB[h2];
                pB[h2] = *(const uint4*)(WtB + widx);
                pC[h2] = *(const uint4*)(WtC + widx);
            }
        }
#pragma unroll
        for (int ks = 0; ks < BK; ks += 32) {
            short8 af[4], bf[2];
#pragma unroll
            for (int mt = 0; mt < 4; ++mt)
                af[mt] = *(const short8*)&As[wm * 64 + mt * 16 + l16][ks + quad * 8];
#pragma unroll
            for (int nt = 0; nt < 2; ++nt)
                bf[nt] = *(const short8*)&Bs[wn * 32 + nt * 16 + l16][ks + quad * 8];
#pragma unroll
            for (int mt = 0; mt < 4; ++mt)
#pragma unroll
                for (int nt = 0; nt < 2; ++nt)
                    acc1[mt][nt] = __builtin_amdgcn_mfma_f32_16x16x32_bf16(af[mt], bf[nt], acc1[mt][nt], 0, 0, 0);
        }
    }
    // ===== phase 2: acc1 += h @ Wu1^T ; acc2 += h @ M2^T, prefetch-pipelined =====
    for (int k0 = 0; k0 < NDIM; k0 += BK) {
        __syncthreads();
#pragma unroll
        for (int h2 = 0; h2 < 4; ++h2) *(uint4*)&As[rA[h2]][koA[h2]] = pA[h2];
#pragma unroll
        for (int h2 = 0; h2 < 2; ++h2) {
            *(uint4*)&Bs[rB[h2]][koB[h2]] = pB[h2];
            *(uint4*)&Cs[rB[h2]][koB[h2]] = pC[h2];
        }
        __syncthreads();
        int k1 = k0 + BK;
        if (k1 < NDIM) {
#pragma unroll
            for (int h2 = 0; h2 < 4; ++h2)
                pA[h2] = *(const uint4*)(hcur + (size_t)growA[h2] * NDIM + k1 + koA[h2]);
#pragma unroll
            for (int h2 = 0; h2 < 2; ++h2) {
                size_t widx = (size_t)(n0 + rB[h2]) * NDIM + k1 + koB[h2];
                pB[h2] = *(const uint4*)(WtB + widx);
                pC[h2] = *(const uint4*)(WtC + widx);
            }
        }
#pragma unroll
        for (int ks = 0; ks < BK; ks += 32) {
            short8 af[4], bf[2], cf[2];
#pragma unroll
            for (int mt = 0; mt < 4; ++mt)
                af[mt] = *(const short8*)&As[wm * 64 + mt * 16 + l16][ks + quad * 8];
#pragma unroll
            for (int nt = 0; nt < 2; ++nt) {
                bf[nt] = *(const short8*)&Bs[wn * 32 + nt * 16 + l16][ks + quad * 8];
                cf[nt] = *(const short8*)&Cs[wn * 32 + nt * 16 + l16][ks + quad * 8];
            }
#pragma unroll
            for (int mt = 0; mt < 4; ++mt)
#pragma unroll
                for (int nt = 0; nt < 2; ++nt) {
                    acc1[mt][nt] = __builtin_amdgcn_mfma_f32_16x16x32_bf16(af[mt], bf[nt], acc1[mt][nt], 0, 0, 0);
                    acc2[mt][nt] = __builtin_amdgcn_mfma_f32_16x16x32_bf16(af[mt], cf[nt], acc2[mt][nt], 0, 0, 0);
                }
        }
    }
    // epilogue
#pragma unroll
    for (int mt = 0; mt < 4; ++mt) {
#pragma unroll
        for (int nt = 0; nt < 2; ++nt) {
            int lcol = wn * 32 + nt * 16 + l16;
            int col = n0 + lcol;
            float bu = bupd[col];
            float cv = cvec[col];
            float cmax = 0.f;
#pragma unroll
            for (int r = 0; r < 4; ++r) {
                int row = row0 + wm * 64 + mt * 16 + quad * 4 + r;
                if (row < n) {
                    float dg = (float)deg[row];
                    float v = fmaxf(acc1[mt][nt][r] + dg * (acc2[mt][nt][r] + cv) + bu, 0.f);
                    Out[(size_t)row * NDIM + col] = f2b(v);
                    if (!LAST) Out8[(size_t)row * NDIM + col] = f2fp8(v);
                    if (LAST) cmax = fmaxf(cmax, v);
                }
            }
            if (LAST) atomicMax(&smax[lcol], __float_as_int(cmax));
        }
    }
    if (LAST) {
        __syncthreads();
        if (t < BN) atomicMax(&geInt[n0 + t], smax[t]);
    }
}

// ---------- final ----------
__global__ __launch_bounds__(1024) void out_kernel(const float* __restrict__ ge,
                                                   const float* __restrict__ W_out,
                                                   const float* __restrict__ b_out,
                                                   float* __restrict__ out) {
    __shared__ float red[4][NDIM];
    int t = threadIdx.x & 255;
    int g = threadIdx.x >> 8;
    float acc = 0.f;
#pragma unroll 8
    for (int kk = 0; kk < 64; ++kk) {
        int k = g * 64 + kk;
        acc += ge[k] * W_out[k * NDIM + t];
    }
    red[g][t] = acc;
    __syncthreads();
    if (g == 0)
        out[t] = b_out[t] + red[0][t] + red[1][t] + red[2][t] + red[3][t];
}

// ---------- launch ----------
extern "C" void kernel_launch(void* const* d_in, const int* in_sizes, int n_in,
                              void* d_out, int out_size, void* d_ws, size_t ws_size,
                              hipStream_t stream) {
    const float* nodes      = (const float*)d_in[0];
    const int*   edges      = (const int*)d_in[1];
    const int*   node_types = (const int*)d_in[2];
    const float* type_emb   = (const float*)d_in[3];
    const float* W_proj     = (const float*)d_in[4];
    const float* b_proj     = (const float*)d_in[5];
    const float* W_msg      = (const float*)d_in[6];
    const float* b_msg      = (const float*)d_in[7];
    const float* W_upd      = (const float*)d_in[8];
    const float* b_upd      = (const float*)d_in[9];
    const float* W_out      = (const float*)d_in[10];
    const float* b_out      = (const float*)d_in[11];

    int n = in_sizes[2];
    int E = in_sizes[1] / 2;
    const int* src = edges;
    const int* dst = edges + E;

    size_t off = 0;
    auto alloc = [&](size_t bytes) {
        void* p = (char*)d_ws + off;
        off += (bytes + 255) & ~(size_t)255;
        return p;
    };
    int* deg    = (int*)alloc((size_t)(n + 4096) * 4);
    int* rowptr = (int*)alloc((size_t)(n + 1) * 4);
    int* cursor = (int*)alloc((size_t)n * 4);
    int* col    = (int*)alloc((size_t)(E + 8 * n) * 4);
    unsigned short* WtA = (unsigned short*)alloc((size_t)HOPS * 256 * 256 * 2);
    unsigned short* WtB = (unsigned short*)alloc((size_t)HOPS * 256 * 256 * 2);
    unsigned short* WtC = (unsigned short*)alloc((size_t)HOPS * 256 * 256 * 2);
    float* cvec = (float*)alloc((size_t)HOPS * 256 * 4);
    int* geInt  = (int*)alloc((size_t)256 * 4);
    unsigned short* hA  = (unsigned short*)alloc((size_t)(n + 1) * NDIM * 2);
    unsigned short* hB  = (unsigned short*)alloc((size_t)(n + 1) * NDIM * 2);
    unsigned short* Sb  = (unsigned short*)alloc((size_t)n * NDIM * 2);
    unsigned char* h8   = (unsigned char*)alloc((size_t)(n + 1) * NDIM);

    hipMemsetAsync(deg, 0, (size_t)(n + 4096) * 4, stream);
    int eb = (E + 255) / 256;
    hist_kernel<<<eb, 256, 0, stream>>>(dst, deg, E);
    scan_kernel<<<1, 1024, 0, stream>>>(deg, rowptr, cursor, n);
    fill_kernel<<<eb, 256, 0, stream>>>(src, dst, cursor, col, E);
    pad_kernel<<<(n + 255) / 256, 256, 0, stream>>>(rowptr, deg, col, n);
    wprep_kernel<<<389, 256, 0, stream>>>(W_msg, W_upd, b_msg, WtA, WtB, WtC, cvec,
                                          geInt, h8 + (size_t)n * NDIM);
    init_h_kernel<<<n, 256, 0, stream>>>(nodes, node_types, type_emb, W_proj, b_proj, hA, h8, n);

    unsigned short* h  = hA;
    unsigned short* ho = hB;
    int gx = (n + BM - 1) / BM;
    dim3 ggrid(gx, NDIM / BN);
    for (int i = 0; i < HOPS; ++i) {
        agg_kernel<<<(n + 7) / 8, 256, 0, stream>>>(h8, rowptr, col, Sb, n);
        size_t wofs = (size_t)i * 256 * 256;
        if (i == HOPS - 1)
            gemm_hop_kernel<true><<<ggrid, 256, 0, stream>>>(
                Sb, h, deg, WtA + wofs, WtB + wofs, WtC + wofs,
                b_upd + (size_t)i * NDIM, cvec + (size_t)i * NDIM, ho, h8, geInt, n);
        else
            gemm_hop_kernel<false><<<ggrid, 256, 0, stream>>>(
                Sb, h, deg, WtA + wofs, WtB + wofs, WtC + wofs,
                b_upd + (size_t)i * NDIM, cvec + (size_t)i * NDIM, ho, h8, geInt, n);
        unsigned short* tmp = h; h = ho; ho = tmp;
    }
    out_kernel<<<1, 1024, 0, stream>>>((const float*)geInt, W_out, b_out, (float*)d_out);
}

// Round 22
// 395.332 us; speedup vs baseline: 1.4621x; 1.4621x over previous
//
#include <hip/hip_runtime.h>
#include <hip/hip_bf16.h>

#define NDIM 256
#define FDIM 32
#define HOPS 4

typedef __attribute__((ext_vector_type(8))) short short8;
typedef __attribute__((ext_vector_type(4))) float f32x4;
typedef __attribute__((ext_vector_type(2))) float f32x2;

// ---------- helpers ----------
__device__ inline float b2f(unsigned short u) {
    union { unsigned int i; float f; } v; v.i = ((unsigned int)u) << 16; return v.f;
}
__device__ inline unsigned short f2b(float f) {
    union { float f; unsigned int i; } v; v.f = f;
    unsigned int r = v.i + 0x7FFF + ((v.i >> 16) & 1);
    return (unsigned short)(r >> 16);
}
__device__ inline unsigned char f2fp8(float v) {
    return (unsigned char)(__builtin_amdgcn_cvt_pk_fp8_f32(v, v, 0, false) & 0xFF);
}

// ---------- CSR build ----------
__global__ void hist_kernel(const int* __restrict__ dst, int* __restrict__ deg, int E) {
    int e = blockIdx.x * blockDim.x + threadIdx.x;
    if (e < E) atomicAdd(&deg[dst[e]], 1);
}

// 1024-thread scan over degree-PADDED (multiple of 8) counts, int4-batched.
__global__ __launch_bounds__(1024) void scan_kernel(const int* __restrict__ deg,
                                                    int* __restrict__ rowptr,
                                                    int* __restrict__ cursor, int n) {
    __shared__ int wsum[16];
    int t = threadIdx.x;
    int per4 = (n + 4095) >> 12;
    int base = t * per4 * 4;
    int4 v4[8];
#pragma unroll 8
    for (int j = 0; j < per4; ++j) {
        int4 d = *(const int4*)(deg + base + j * 4);
        d.x = (d.x + 7) & ~7; d.y = (d.y + 7) & ~7;
        d.z = (d.z + 7) & ~7; d.w = (d.w + 7) & ~7;
        v4[j] = d;
    }
    int s = 0;
#pragma unroll 8
    for (int j = 0; j < per4; ++j) s += v4[j].x + v4[j].y + v4[j].z + v4[j].w;

    int lane = t & 63, wid = t >> 6;
    int v = s;
#pragma unroll
    for (int d = 1; d < 64; d <<= 1) {
        int u = __shfl_up(v, d, 64);
        if (lane >= d) v += u;
    }
    if (lane == 63) wsum[wid] = v;
    __syncthreads();
    if (wid == 0) {
        int ws = (lane < 16) ? wsum[lane] : 0;
#pragma unroll
        for (int d = 1; d < 16; d <<= 1) {
            int u = __shfl_up(ws, d, 64);
            if (lane >= d) ws += u;
        }
        if (lane < 16) wsum[lane] = ws;
    }
    __syncthreads();
    int run = (wid > 0 ? wsum[wid - 1] : 0) + (v - s);
#pragma unroll 8
    for (int j = 0; j < per4; ++j) {
        int idx = base + j * 4;
        int4 o;
        o.x = run; run += v4[j].x;
        o.y = run; run += v4[j].y;
        o.z = run; run += v4[j].z;
        o.w = run; run += v4[j].w;
        if (idx + 3 < n) {
            *(int4*)(rowptr + idx) = o;
            *(int4*)(cursor + idx) = o;
        } else if (idx < n) {
            const int* op = (const int*)&o;
            for (int e = 0; e < 4 && idx + e < n; ++e) {
                rowptr[idx + e] = op[e];
                cursor[idx + e] = op[e];
            }
        }
    }
    if (t == 1023) rowptr[n] = run;
}

__global__ void fill_kernel(const int* __restrict__ src, const int* __restrict__ dst,
                            int* __restrict__ cursor, int* __restrict__ col, int E) {
    int e = blockIdx.x * blockDim.x + threadIdx.x;
    if (e < E) {
        int d = dst[e];
        int p = atomicAdd(&cursor[d], 1);
        col[p] = src[e];
    }
}

// fill pad slots [rowptr[v]+deg[v], rowptr[v+1]) with index n (zero row)
__global__ void pad_kernel(const int* __restrict__ rowptr, const int* __restrict__ deg,
                           int* __restrict__ col, int n) {
    int v = blockIdx.x * blockDim.x + threadIdx.x;
    if (v < n) {
        int s = rowptr[v] + deg[v];
        int e = rowptr[v + 1];
        for (int i = s; i < e; ++i) col[i] = n;
    }
}

// ---------- merged weight prep: wtrans (0..255) + mm (256..383) + cvec (384..387) + zero (388) ----------
__global__ __launch_bounds__(256) void wprep_kernel(const float* __restrict__ Wm,
                                                    const float* __restrict__ Wu,
                                                    const float* __restrict__ bm,
                                                    unsigned short* __restrict__ WtA,
                                                    unsigned short* __restrict__ WtB,
                                                    unsigned short* __restrict__ WtC,
                                                    float* __restrict__ cvec,
                                                    int* __restrict__ geInt,
                                                    unsigned char* __restrict__ h8row) {
    __shared__ float T[32][33];
    __shared__ float Af[32][68];
    __shared__ float Bf[32][68];
    __shared__ float sb[256];
    int b = blockIdx.x;
    int t = threadIdx.x;

    if (b < 256) {
        int hop = b >> 6;
        int rem = b & 63;
        int k0 = (rem & 7) * 32, n0 = (rem >> 3) * 32;
        const float* src = Wu + (size_t)hop * 512 * 256;
        unsigned short* dstp = WtB + (size_t)hop * 256 * 256;
        int tr = t >> 5, tc = t & 31;
#pragma unroll
        for (int r = 0; r < 4; ++r) {
            int k = tr + r * 8;
            T[tc][k] = src[(size_t)(k0 + k) * 256 + n0 + tc];
        }
        __syncthreads();
#pragma unroll
        for (int r = 0; r < 4; ++r) {
            int nn = tr + r * 8;
            dstp[(size_t)(n0 + nn) * 256 + k0 + tc] = f2b(T[nn][tc]);
        }
    } else if (b < 384) {
        int idx = b - 256;
        int m = idx >> 4;
        int rem = idx & 15;
        int k0 = (rem & 3) * 64, n0 = (rem >> 2) * 64;
        int hop = m >> 1, which = m & 1;
        const float* A = Wm + (size_t)hop * 512 * 256 + (size_t)which * 256 * 256;
        const float* B = Wu + (size_t)hop * 512 * 256 + (size_t)256 * 256;
        unsigned short* W = (which ? WtC : WtA) + (size_t)hop * 256 * 256;
        int tx = t & 15, ty = t >> 4;
        float acc[4][4];
#pragma unroll
        for (int a = 0; a < 4; ++a)
#pragma unroll
            for (int c = 0; c < 4; ++c) acc[a][c] = 0.f;

        for (int j0 = 0; j0 < 256; j0 += 32) {
            __syncthreads();
#pragma unroll
            for (int c = 0; c < 2; ++c) {
                int idx2 = t + c * 256;
                int kk = idx2 >> 3;
                int jj = (idx2 & 7) * 4;
                float4 va = *(const float4*)&A[(size_t)(k0 + kk) * 256 + j0 + jj];
                Af[jj + 0][kk] = va.x; Af[jj + 1][kk] = va.y;
                Af[jj + 2][kk] = va.z; Af[jj + 3][kk] = va.w;
                int jj2 = idx2 >> 4;
                int nn = (idx2 & 15) * 4;
                float4 vb = *(const float4*)&B[(size_t)(j0 + jj2) * 256 + n0 + nn];
                *(float4*)&Bf[jj2][nn] = vb;
            }
            __syncthreads();
#pragma unroll
            for (int jj = 0; jj < 32; ++jj) {
                float av[4];
#pragma unroll
                for (int a = 0; a < 4; ++a) av[a] = Af[jj][ty * 4 + a];
                float4 bv = *(const float4*)&Bf[jj][tx * 4];
#pragma unroll
                for (int a = 0; a < 4; ++a) {
                    acc[a][0] += av[a] * bv.x; acc[a][1] += av[a] * bv.y;
                    acc[a][2] += av[a] * bv.z; acc[a][3] += av[a] * bv.w;
                }
            }
        }
#pragma unroll
        for (int c = 0; c < 4; ++c) {
            int nn = n0 + tx * 4 + c;
            ushort4 o;
            o.x = f2b(acc[0][c]); o.y = f2b(acc[1][c]);
            o.z = f2b(acc[2][c]); o.w = f2b(acc[3][c]);
            *(ushort4*)&W[(size_t)nn * 256 + k0 + ty * 4] = o;
        }
    } else if (b < 388) {
        int hop = b - 384;
        sb[t] = bm[hop * 256 + t];
        __syncthreads();
        const float* B = Wu + (size_t)hop * 512 * 256 + (size_t)256 * 256;
        float acc = 0.f;
#pragma unroll 8
        for (int j = 0; j < 256; ++j) acc += sb[j] * B[(size_t)j * 256 + t];
        cvec[hop * 256 + t] = acc;
    } else {
        geInt[t] = 0;
        h8row[t] = 0;
    }
}

// ---------- initial projection (writes bf16 h + fp8 h8) ----------
__global__ void init_h_kernel(const float* __restrict__ nodes,
                              const int* __restrict__ node_types,
                              const float* __restrict__ type_emb,
                              const float* __restrict__ W_proj,
                              const float* __restrict__ b_proj,
                              unsigned short* __restrict__ h,
                              unsigned char* __restrict__ h8, int n) {
    int v = blockIdx.x;
    int t = threadIdx.x;
    __shared__ float sn[FDIM];
    if (t < FDIM) sn[t] = nodes[v * FDIM + t];
    __syncthreads();
    int ty = node_types[v];
    float acc = b_proj[t] + type_emb[ty * NDIM + t];
#pragma unroll
    for (int k = 0; k < FDIM; ++k) acc += sn[k] * W_proj[k * NDIM + t];
    h[(size_t)v * NDIM + t] = f2b(acc);
    h8[(size_t)v * NDIM + t] = f2fp8(acc);
}

// ---------- neighbor sum: fp8 gather (256B rows), fp32 accumulate, bf16 out ----------
__global__ __launch_bounds__(256) void agg_kernel(const unsigned char* __restrict__ h8,
                                                  const int* __restrict__ rowptr,
                                                  const int* __restrict__ col,
                                                  unsigned short* __restrict__ S, int n) {
    int wave = threadIdx.x >> 6;
    int lane = threadIdx.x & 63;
    int half = lane >> 5;
    int hl = lane & 31;
    int v = blockIdx.x * 8 + wave * 2 + half;
    if (v >= n) return;
    int beg = rowptr[v], end = rowptr[v + 1];
    float a[8];
#pragma unroll
    for (int e = 0; e < 8; ++e) a[e] = 0.f;
    int cofs = hl * 8;
    for (int i = beg; i < end; i += 8) {
        int cc[8];
#pragma unroll
        for (int j = 0; j < 8; ++j) cc[j] = col[i + j];
        uint2 x[8];
#pragma unroll
        for (int j = 0; j < 8; ++j)
            x[j] = *(const uint2*)(h8 + (size_t)cc[j] * NDIM + cofs);
#pragma unroll
        for (int j = 0; j < 8; ++j) {
            f32x2 p0 = __builtin_amdgcn_cvt_pk_f32_fp8(x[j].x, false);
            f32x2 p1 = __builtin_amdgcn_cvt_pk_f32_fp8(x[j].x, true);
            f32x2 p2 = __builtin_amdgcn_cvt_pk_f32_fp8(x[j].y, false);
            f32x2 p3 = __builtin_amdgcn_cvt_pk_f32_fp8(x[j].y, true);
            a[0] += p0[0]; a[1] += p0[1]; a[2] += p1[0]; a[3] += p1[1];
            a[4] += p2[0]; a[5] += p2[1]; a[6] += p3[0]; a[7] += p3[1];
        }
    }
    uint4 o;
    unsigned short* op = (unsigned short*)&o;
#pragma unroll
    for (int e = 0; e < 8; ++e) op[e] = f2b(a[e]);
    *(uint4*)&S[(size_t)v * NDIM + cofs] = o;
}

// ---------- fused hop GEMM: BM=128 BN=64 BK=64 two-phase dual-acc (R20 config) ----------
#define BM 128
#define BN 64
#define BK 64
#define ASTR (BK + 8)

template <bool LAST>
__global__ __launch_bounds__(256) void gemm_hop_kernel(const unsigned short* __restrict__ S,
                                                       const unsigned short* __restrict__ hcur,
                                                       const int* __restrict__ deg,
                                                       const unsigned short* __restrict__ WtA,
                                                       const unsigned short* __restrict__ WtB,
                                                       const unsigned short* __restrict__ WtC,
                                                       const float* __restrict__ bupd,
                                                       const float* __restrict__ cvec,
                                                       unsigned short* __restrict__ Out,
                                                       unsigned char* __restrict__ Out8,
                                                       int* __restrict__ geInt, int n) {
    __shared__ unsigned short As[BM][ASTR];
    __shared__ unsigned short Bs[BN][ASTR];
    __shared__ unsigned short Cs[BN][ASTR];
    __shared__ int smax[BN];
    int t = threadIdx.x;
    int lane = t & 63;
    int w = t >> 6;
    int wm = w >> 1, wn = w & 1;
    int quad = lane >> 4, l16 = lane & 15;
    int row0 = blockIdx.x * BM;
    int n0 = blockIdx.y * BN;

    if (LAST) {
        if (t < BN) smax[t] = 0;
    }

    f32x4 acc1[4][2], acc2[4][2];
#pragma unroll
    for (int i = 0; i < 4; ++i)
#pragma unroll
        for (int j = 0; j < 2; ++j) { acc1[i][j] = (f32x4)(0.f); acc2[i][j] = (f32x4)(0.f); }

    // phase 1: acc1 += S @ M1^T
    for (int k0 = 0; k0 < NDIM; k0 += BK) {
        __syncthreads();
#pragma unroll
        for (int h2 = 0; h2 < 4; ++h2) {
            int c = t + h2 * 256;
            int r = c >> 3;
            int ko = (c & 7) * 8;
            int grow = row0 + r; if (grow >= n) grow = n - 1;
            *(uint4*)&As[r][ko] = *(const uint4*)(S + (size_t)grow * NDIM + k0 + ko);
        }
#pragma unroll
        for (int h2 = 0; h2 < 2; ++h2) {
            int c = t + h2 * 256;
            int r = c >> 3;
            int ko = (c & 7) * 8;
            *(uint4*)&Bs[r][ko] = *(const uint4*)(WtA + (size_t)(n0 + r) * NDIM + k0 + ko);
        }
        __syncthreads();
#pragma unroll
        for (int ks = 0; ks < BK; ks += 32) {
            short8 af[4], bf[2];
#pragma unroll
            for (int mt = 0; mt < 4; ++mt)
                af[mt] = *(const short8*)&As[wm * 64 + mt * 16 + l16][ks + quad * 8];
#pragma unroll
            for (int nt = 0; nt < 2; ++nt)
                bf[nt] = *(const short8*)&Bs[wn * 32 + nt * 16 + l16][ks + quad * 8];
#pragma unroll
            for (int mt = 0; mt < 4; ++mt)
#pragma unroll
                for (int nt = 0; nt < 2; ++nt)
                    acc1[mt][nt] = __builtin_amdgcn_mfma_f32_16x16x32_bf16(af[mt], bf[nt], acc1[mt][nt], 0, 0, 0);
        }
    }
    // phase 2: acc1 += h @ Wu1^T ; acc2 += h @ M2^T
    for (int k0 = 0; k0 < NDIM; k0 += BK) {
        __syncthreads();
#pragma unroll
        for (int h2 = 0; h2 < 4; ++h2) {
            int c = t + h2 * 256;
            int r = c >> 3;
            int ko = (c & 7) * 8;
            int grow = row0 + r; if (grow >= n) grow = n - 1;
            *(uint4*)&As[r][ko] = *(const uint4*)(hcur + (size_t)grow * NDIM + k0 + ko);
        }
#pragma unroll
        for (int h2 = 0; h2 < 2; ++h2) {
            int c = t + h2 * 256;
            int r = c >> 3;
            int ko = (c & 7) * 8;
            size_t widx = (size_t)(n0 + r) * NDIM + k0 + ko;
            *(uint4*)&Bs[r][ko] = *(const uint4*)(WtB + widx);
            *(uint4*)&Cs[r][ko] = *(const uint4*)(WtC + widx);
        }
        __syncthreads();
#pragma unroll
        for (int ks = 0; ks < BK; ks += 32) {
            short8 af[4], bf[2], cf[2];
#pragma unroll
            for (int mt = 0; mt < 4; ++mt)
                af[mt] = *(const short8*)&As[wm * 64 + mt * 16 + l16][ks + quad * 8];
#pragma unroll
            for (int nt = 0; nt < 2; ++nt) {
                bf[nt] = *(const short8*)&Bs[wn * 32 + nt * 16 + l16][ks + quad * 8];
                cf[nt] = *(const short8*)&Cs[wn * 32 + nt * 16 + l16][ks + quad * 8];
            }
#pragma unroll
            for (int mt = 0; mt < 4; ++mt)
#pragma unroll
                for (int nt = 0; nt < 2; ++nt) {
                    acc1[mt][nt] = __builtin_amdgcn_mfma_f32_16x16x32_bf16(af[mt], bf[nt], acc1[mt][nt], 0, 0, 0);
                    acc2[mt][nt] = __builtin_amdgcn_mfma_f32_16x16x32_bf16(af[mt], cf[nt], acc2[mt][nt], 0, 0, 0);
                }
        }
    }
    // epilogue
#pragma unroll
    for (int mt = 0; mt < 4; ++mt) {
#pragma unroll
        for (int nt = 0; nt < 2; ++nt) {
            int lcol = wn * 32 + nt * 16 + l16;
            int col = n0 + lcol;
            float bu = bupd[col];
            float cv = cvec[col];
            float cmax = 0.f;
#pragma unroll
            for (int r = 0; r < 4; ++r) {
                int row = row0 + wm * 64 + mt * 16 + quad * 4 + r;
                if (row < n) {
                    float dg = (float)deg[row];
                    float v = fmaxf(acc1[mt][nt][r] + dg * (acc2[mt][nt][r] + cv) + bu, 0.f);
                    Out[(size_t)row * NDIM + col] = f2b(v);
                    if (!LAST) Out8[(size_t)row * NDIM + col] = f2fp8(v);
                    if (LAST) cmax = fmaxf(cmax, v);
                }
            }
            if (LAST) atomicMax(&smax[lcol], __float_as_int(cmax));
        }
    }
    if (LAST) {
        __syncthreads();
        if (t < BN) atomicMax(&geInt[n0 + t], smax[t]);
    }
}

// ---------- final ----------
__global__ __launch_bounds__(1024) void out_kernel(const float* __restrict__ ge,
                                                   const float* __restrict__ W_out,
                                                   const float* __restrict__ b_out,
                                                   float* __restrict__ out) {
    __shared__ float red[4][NDIM];
    int t = threadIdx.x & 255;
    int g = threadIdx.x >> 8;
    float acc = 0.f;
#pragma unroll 8
    for (int kk = 0; kk < 64; ++kk) {
        int k = g * 64 + kk;
        acc += ge[k] * W_out[k * NDIM + t];
    }
    red[g][t] = acc;
    __syncthreads();
    if (g == 0)
        out[t] = b_out[t] + red[0][t] + red[1][t] + red[2][t] + red[3][t];
}

// ---------- launch ----------
extern "C" void kernel_launch(void* const* d_in, const int* in_sizes, int n_in,
                              void* d_out, int out_size, void* d_ws, size_t ws_size,
                              hipStream_t stream) {
    const float* nodes      = (const float*)d_in[0];
    const int*   edges      = (const int*)d_in[1];
    const int*   node_types = (const int*)d_in[2];
    const float* type_emb   = (const float*)d_in[3];
    const float* W_proj     = (const float*)d_in[4];
    const float* b_proj     = (const float*)d_in[5];
    const float* W_msg      = (const float*)d_in[6];
    const float* b_msg      = (const float*)d_in[7];
    const float* W_upd      = (const float*)d_in[8];
    const float* b_upd      = (const float*)d_in[9];
    const float* W_out      = (const float*)d_in[10];
    const float* b_out      = (const float*)d_in[11];

    int n = in_sizes[2];
    int E = in_sizes[1] / 2;
    const int* src = edges;
    const int* dst = edges + E;

    size_t off = 0;
    auto alloc = [&](size_t bytes) {
        void* p = (char*)d_ws + off;
        off += (bytes + 255) & ~(size_t)255;
        return p;
    };
    int* deg    = (int*)alloc((size_t)(n + 4096) * 4);
    int* rowptr = (int*)alloc((size_t)(n + 1) * 4);
    int* cursor = (int*)alloc((size_t)n * 4);
    int* col    = (int*)alloc((size_t)(E + 8 * n) * 4);
    unsigned short* WtA = (unsigned short*)alloc((size_t)HOPS * 256 * 256 * 2);
    unsigned short* WtB = (unsigned short*)alloc((size_t)HOPS * 256 * 256 * 2);
    unsigned short* WtC = (unsigned short*)alloc((size_t)HOPS * 256 * 256 * 2);
    float* cvec = (float*)alloc((size_t)HOPS * 256 * 4);
    int* geInt  = (int*)alloc((size_t)256 * 4);
    unsigned short* hA  = (unsigned short*)alloc((size_t)(n + 1) * NDIM * 2);
    unsigned short* hB  = (unsigned short*)alloc((size_t)(n + 1) * NDIM * 2);
    unsigned short* Sb  = (unsigned short*)alloc((size_t)n * NDIM * 2);
    unsigned char* h8   = (unsigned char*)alloc((size_t)(n + 1) * NDIM);

    hipMemsetAsync(deg, 0, (size_t)(n + 4096) * 4, stream);
    int eb = (E + 255) / 256;
    hist_kernel<<<eb, 256, 0, stream>>>(dst, deg, E);
    scan_kernel<<<1, 1024, 0, stream>>>(deg, rowptr, cursor, n);
    fill_kernel<<<eb, 256, 0, stream>>>(src, dst, cursor, col, E);
    pad_kernel<<<(n + 255) / 256, 256, 0, stream>>>(rowptr, deg, col, n);
    wprep_kernel<<<389, 256, 0, stream>>>(W_msg, W_upd, b_msg, WtA, WtB, WtC, cvec,
                                          geInt, h8 + (size_t)n * NDIM);
    init_h_kernel<<<n, 256, 0, stream>>>(nodes, node_types, type_emb, W_proj, b_proj, hA, h8, n);

    unsigned short* h  = hA;
    unsigned short* ho = hB;
    int gx = (n + BM - 1) / BM;
    dim3 ggrid(gx, NDIM / BN);
    for (int i = 0; i < HOPS; ++i) {
        agg_kernel<<<(n + 7) / 8, 256, 0, stream>>>(h8, rowptr, col, Sb, n);
        size_t wofs = (size_t)i * 256 * 256;
        if (i == HOPS - 1)
            gemm_hop_kernel<true><<<ggrid, 256, 0, stream>>>(
                Sb, h, deg, WtA + wofs, WtB + wofs, WtC + wofs,
                b_upd + (size_t)i * NDIM, cvec + (size_t)i * NDIM, ho, h8, geInt, n);
        else
            gemm_hop_kernel<false><<<ggrid, 256, 0, stream>>>(
                Sb, h, deg, WtA + wofs, WtB + wofs, WtC + wofs,
                b_upd + (size_t)i * NDIM, cvec + (size_t)i * NDIM, ho, h8, geInt, n);
        unsigned short* tmp = h; h = ho; ho = tmp;
    }
    out_kernel<<<1, 1024, 0, stream>>>((const float*)geInt, W_out, b_out, (float*)d_out);
}

// Round 23
// 380.683 us; speedup vs baseline: 1.5183x; 1.0385x over previous
//
#include <hip/hip_runtime.h>
#include <hip/hip_bf16.h>

#define NDIM 256
#define FDIM 32
#define HOPS 4

typedef __attribute__((ext_vector_type(8))) short short8;
typedef __attribute__((ext_vector_type(4))) float f32x4;
typedef __attribute__((ext_vector_type(2))) float f32x2;

// ---------- helpers ----------
__device__ inline float b2f(unsigned short u) {
    union { unsigned int i; float f; } v; v.i = ((unsigned int)u) << 16; return v.f;
}
__device__ inline unsigned short f2b(float f) {
    union { float f; unsigned int i; } v; v.f = f;
    unsigned int r = v.i + 0x7FFF + ((v.i >> 16) & 1);
    return (unsigned short)(r >> 16);
}
__device__ inline unsigned char f2fp8(float v) {
    return (unsigned char)(__builtin_amdgcn_cvt_pk_fp8_f32(v, v, 0, false) & 0xFF);
}

// ---------- prep mega: hist (blocks 0..histB-1) + wprep (histB..histB+388) + init_h (rest) ----------
__global__ __launch_bounds__(256) void prep_mega_kernel(
        const int* __restrict__ dst, int* __restrict__ deg, int E, int histB,
        const float* __restrict__ Wm, const float* __restrict__ Wu,
        const float* __restrict__ bm,
        unsigned short* __restrict__ WtA, unsigned short* __restrict__ WtB,
        unsigned short* __restrict__ WtC,
        float* __restrict__ cvec, int* __restrict__ geInt,
        unsigned char* __restrict__ h8row,
        const float* __restrict__ nodes, const int* __restrict__ node_types,
        const float* __restrict__ type_emb, const float* __restrict__ W_proj,
        const float* __restrict__ b_proj,
        unsigned short* __restrict__ h, unsigned char* __restrict__ h8, int n) {
    __shared__ float T[32][33];
    __shared__ float Af[32][68];
    __shared__ float Bf[32][68];
    __shared__ float sb[256];
    int b = blockIdx.x;
    int t = threadIdx.x;

    if (b < histB) {
        // ---- hist ----
        int e = b * 256 + t;
        if (e < E) atomicAdd(&deg[dst[e]], 1);
    } else if (b < histB + 389) {
        int bb = b - histB;
        if (bb < 256) {
            // ---- wtrans: WtB[hop][nn][k] = W_upd[hop][k][nn] ----
            int hop = bb >> 6;
            int rem = bb & 63;
            int k0 = (rem & 7) * 32, n0 = (rem >> 3) * 32;
            const float* src = Wu + (size_t)hop * 512 * 256;
            unsigned short* dstp = WtB + (size_t)hop * 256 * 256;
            int tr = t >> 5, tc = t & 31;
#pragma unroll
            for (int r = 0; r < 4; ++r) {
                int k = tr + r * 8;
                T[tc][k] = src[(size_t)(k0 + k) * 256 + n0 + tc];
            }
            __syncthreads();
#pragma unroll
            for (int r = 0; r < 4; ++r) {
                int nn = tr + r * 8;
                dstp[(size_t)(n0 + nn) * 256 + k0 + tc] = f2b(T[nn][tc]);
            }
        } else if (bb < 384) {
            // ---- mm: M = Wm_half @ Wu2, stored transposed ----
            int idx = bb - 256;
            int m = idx >> 4;
            int rem = idx & 15;
            int k0 = (rem & 3) * 64, n0 = (rem >> 2) * 64;
            int hop = m >> 1, which = m & 1;
            const float* A = Wm + (size_t)hop * 512 * 256 + (size_t)which * 256 * 256;
            const float* B = Wu + (size_t)hop * 512 * 256 + (size_t)256 * 256;
            unsigned short* W = (which ? WtC : WtA) + (size_t)hop * 256 * 256;
            int tx = t & 15, ty = t >> 4;
            float acc[4][4];
#pragma unroll
            for (int a = 0; a < 4; ++a)
#pragma unroll
                for (int c = 0; c < 4; ++c) acc[a][c] = 0.f;

            for (int j0 = 0; j0 < 256; j0 += 32) {
                __syncthreads();
#pragma unroll
                for (int c = 0; c < 2; ++c) {
                    int idx2 = t + c * 256;
                    int kk = idx2 >> 3;
                    int jj = (idx2 & 7) * 4;
                    float4 va = *(const float4*)&A[(size_t)(k0 + kk) * 256 + j0 + jj];
                    Af[jj + 0][kk] = va.x; Af[jj + 1][kk] = va.y;
                    Af[jj + 2][kk] = va.z; Af[jj + 3][kk] = va.w;
                    int jj2 = idx2 >> 4;
                    int nn = (idx2 & 15) * 4;
                    float4 vb = *(const float4*)&B[(size_t)(j0 + jj2) * 256 + n0 + nn];
                    *(float4*)&Bf[jj2][nn] = vb;
                }
                __syncthreads();
#pragma unroll
                for (int jj = 0; jj < 32; ++jj) {
                    float av[4];
#pragma unroll
                    for (int a = 0; a < 4; ++a) av[a] = Af[jj][ty * 4 + a];
                    float4 bv = *(const float4*)&Bf[jj][tx * 4];
#pragma unroll
                    for (int a = 0; a < 4; ++a) {
                        acc[a][0] += av[a] * bv.x; acc[a][1] += av[a] * bv.y;
                        acc[a][2] += av[a] * bv.z; acc[a][3] += av[a] * bv.w;
                    }
                }
            }
#pragma unroll
            for (int c = 0; c < 4; ++c) {
                int nn = n0 + tx * 4 + c;
                ushort4 o;
                o.x = f2b(acc[0][c]); o.y = f2b(acc[1][c]);
                o.z = f2b(acc[2][c]); o.w = f2b(acc[3][c]);
                *(ushort4*)&W[(size_t)nn * 256 + k0 + ty * 4] = o;
            }
        } else if (bb < 388) {
            // ---- cvec[hop] = b_msg[hop] @ Wu2[hop] ----
            int hop = bb - 384;
            sb[t] = bm[hop * 256 + t];
            __syncthreads();
            const float* B = Wu + (size_t)hop * 512 * 256 + (size_t)256 * 256;
            float acc = 0.f;
#pragma unroll 8
            for (int j = 0; j < 256; ++j) acc += sb[j] * B[(size_t)j * 256 + t];
            cvec[hop * 256 + t] = acc;
        } else {
            geInt[t] = 0;
            h8row[t] = 0;
        }
    } else {
        // ---- init_h for node v ----
        int v = b - histB - 389;
        if (v < n) {
            if (t < FDIM) sb[t] = nodes[v * FDIM + t];
            __syncthreads();
            int ty = node_types[v];
            float acc = b_proj[t] + type_emb[ty * NDIM + t];
#pragma unroll
            for (int k = 0; k < FDIM; ++k) acc += sb[k] * W_proj[k * NDIM + t];
            h[(size_t)v * NDIM + t] = f2b(acc);
            h8[(size_t)v * NDIM + t] = f2fp8(acc);
        }
    }
}

// 1024-thread scan over degree-PADDED (multiple of 8) counts, int4-batched.
__global__ __launch_bounds__(1024) void scan_kernel(const int* __restrict__ deg,
                                                    int* __restrict__ rowptr,
                                                    int* __restrict__ cursor, int n) {
    __shared__ int wsum[16];
    int t = threadIdx.x;
    int per4 = (n + 4095) >> 12;
    int base = t * per4 * 4;
    int4 v4[8];
#pragma unroll 8
    for (int j = 0; j < per4; ++j) {
        int4 d = *(const int4*)(deg + base + j * 4);
        d.x = (d.x + 7) & ~7; d.y = (d.y + 7) & ~7;
        d.z = (d.z + 7) & ~7; d.w = (d.w + 7) & ~7;
        v4[j] = d;
    }
    int s = 0;
#pragma unroll 8
    for (int j = 0; j < per4; ++j) s += v4[j].x + v4[j].y + v4[j].z + v4[j].w;

    int lane = t & 63, wid = t >> 6;
    int v = s;
#pragma unroll
    for (int d = 1; d < 64; d <<= 1) {
        int u = __shfl_up(v, d, 64);
        if (lane >= d) v += u;
    }
    if (lane == 63) wsum[wid] = v;
    __syncthreads();
    if (wid == 0) {
        int ws = (lane < 16) ? wsum[lane] : 0;
#pragma unroll
        for (int d = 1; d < 16; d <<= 1) {
            int u = __shfl_up(ws, d, 64);
            if (lane >= d) ws += u;
        }
        if (lane < 16) wsum[lane] = ws;
    }
    __syncthreads();
    int run = (wid > 0 ? wsum[wid - 1] : 0) + (v - s);
#pragma unroll 8
    for (int j = 0; j < per4; ++j) {
        int idx = base + j * 4;
        int4 o;
        o.x = run; run += v4[j].x;
        o.y = run; run += v4[j].y;
        o.z = run; run += v4[j].z;
        o.w = run; run += v4[j].w;
        if (idx + 3 < n) {
            *(int4*)(rowptr + idx) = o;
            *(int4*)(cursor + idx) = o;
        } else if (idx < n) {
            const int* op = (const int*)&o;
            for (int e = 0; e < 4 && idx + e < n; ++e) {
                rowptr[idx + e] = op[e];
                cursor[idx + e] = op[e];
            }
        }
    }
    if (t == 1023) rowptr[n] = run;
}

// ---------- fill (blocks 0..fillB-1) + pad (rest); disjoint col ranges ----------
__global__ void fillpad_kernel(const int* __restrict__ src, const int* __restrict__ dst,
                               int* __restrict__ cursor,
                               const int* __restrict__ rowptr, const int* __restrict__ deg,
                               int* __restrict__ col, int E, int fillB, int n) {
    int b = blockIdx.x;
    int t = threadIdx.x;
    if (b < fillB) {
        int e = b * 256 + t;
        if (e < E) {
            int d = dst[e];
            int p = atomicAdd(&cursor[d], 1);
            col[p] = src[e];
        }
    } else {
        int v = (b - fillB) * 256 + t;
        if (v < n) {
            int s = rowptr[v] + deg[v];
            int e0 = rowptr[v + 1];
            for (int i = s; i < e0; ++i) col[i] = n;
        }
    }
}

// ---------- neighbor sum: fp8 gather (256B rows), fp32 accumulate, bf16 out ----------
__global__ __launch_bounds__(256) void agg_kernel(const unsigned char* __restrict__ h8,
                                                  const int* __restrict__ rowptr,
                                                  const int* __restrict__ col,
                                                  unsigned short* __restrict__ S, int n) {
    int wave = threadIdx.x >> 6;
    int lane = threadIdx.x & 63;
    int half = lane >> 5;
    int hl = lane & 31;
    int v = blockIdx.x * 8 + wave * 2 + half;
    if (v >= n) return;
    int beg = rowptr[v], end = rowptr[v + 1];
    float a[8];
#pragma unroll
    for (int e = 0; e < 8; ++e) a[e] = 0.f;
    int cofs = hl * 8;
    for (int i = beg; i < end; i += 8) {
        int cc[8];
#pragma unroll
        for (int j = 0; j < 8; ++j) cc[j] = col[i + j];
        uint2 x[8];
#pragma unroll
        for (int j = 0; j < 8; ++j)
            x[j] = *(const uint2*)(h8 + (size_t)cc[j] * NDIM + cofs);
#pragma unroll
        for (int j = 0; j < 8; ++j) {
            f32x2 p0 = __builtin_amdgcn_cvt_pk_f32_fp8(x[j].x, false);
            f32x2 p1 = __builtin_amdgcn_cvt_pk_f32_fp8(x[j].x, true);
            f32x2 p2 = __builtin_amdgcn_cvt_pk_f32_fp8(x[j].y, false);
            f32x2 p3 = __builtin_amdgcn_cvt_pk_f32_fp8(x[j].y, true);
            a[0] += p0[0]; a[1] += p0[1]; a[2] += p1[0]; a[3] += p1[1];
            a[4] += p2[0]; a[5] += p2[1]; a[6] += p3[0]; a[7] += p3[1];
        }
    }
    uint4 o;
    unsigned short* op = (unsigned short*)&o;
#pragma unroll
    for (int e = 0; e < 8; ++e) op[e] = f2b(a[e]);
    *(uint4*)&S[(size_t)v * NDIM + cofs] = o;
}

// ---------- fused hop GEMM: BM=128 BN=64 BK=64 two-phase dual-acc (R20 config) ----------
#define BM 128
#define BN 64
#define BK 64
#define ASTR (BK + 8)

template <bool LAST>
__global__ __launch_bounds__(256) void gemm_hop_kernel(const unsigned short* __restrict__ S,
                                                       const unsigned short* __restrict__ hcur,
                                                       const int* __restrict__ deg,
                                                       const unsigned short* __restrict__ WtA,
                                                       const unsigned short* __restrict__ WtB,
                                                       const unsigned short* __restrict__ WtC,
                                                       const float* __restrict__ bupd,
                                                       const float* __restrict__ cvec,
                                                       unsigned short* __restrict__ Out,
                                                       unsigned char* __restrict__ Out8,
                                                       int* __restrict__ geInt, int n) {
    __shared__ unsigned short As[BM][ASTR];
    __shared__ unsigned short Bs[BN][ASTR];
    __shared__ unsigned short Cs[BN][ASTR];
    __shared__ int smax[BN];
    int t = threadIdx.x;
    int lane = t & 63;
    int w = t >> 6;
    int wm = w >> 1, wn = w & 1;
    int quad = lane >> 4, l16 = lane & 15;
    int row0 = blockIdx.x * BM;
    int n0 = blockIdx.y * BN;

    if (LAST) {
        if (t < BN) smax[t] = 0;
    }

    f32x4 acc1[4][2], acc2[4][2];
#pragma unroll
    for (int i = 0; i < 4; ++i)
#pragma unroll
        for (int j = 0; j < 2; ++j) { acc1[i][j] = (f32x4)(0.f); acc2[i][j] = (f32x4)(0.f); }

    // phase 1: acc1 += S @ M1^T
    for (int k0 = 0; k0 < NDIM; k0 += BK) {
        __syncthreads();
#pragma unroll
        for (int h2 = 0; h2 < 4; ++h2) {
            int c = t + h2 * 256;
            int r = c >> 3;
            int ko = (c & 7) * 8;
            int grow = row0 + r; if (grow >= n) grow = n - 1;
            *(uint4*)&As[r][ko] = *(const uint4*)(S + (size_t)grow * NDIM + k0 + ko);
        }
#pragma unroll
        for (int h2 = 0; h2 < 2; ++h2) {
            int c = t + h2 * 256;
            int r = c >> 3;
            int ko = (c & 7) * 8;
            *(uint4*)&Bs[r][ko] = *(const uint4*)(WtA + (size_t)(n0 + r) * NDIM + k0 + ko);
        }
        __syncthreads();
#pragma unroll
        for (int ks = 0; ks < BK; ks += 32) {
            short8 af[4], bf[2];
#pragma unroll
            for (int mt = 0; mt < 4; ++mt)
                af[mt] = *(const short8*)&As[wm * 64 + mt * 16 + l16][ks + quad * 8];
#pragma unroll
            for (int nt = 0; nt < 2; ++nt)
                bf[nt] = *(const short8*)&Bs[wn * 32 + nt * 16 + l16][ks + quad * 8];
#pragma unroll
            for (int mt = 0; mt < 4; ++mt)
#pragma unroll
                for (int nt = 0; nt < 2; ++nt)
                    acc1[mt][nt] = __builtin_amdgcn_mfma_f32_16x16x32_bf16(af[mt], bf[nt], acc1[mt][nt], 0, 0, 0);
        }
    }
    // phase 2: acc1 += h @ Wu1^T ; acc2 += h @ M2^T
    for (int k0 = 0; k0 < NDIM; k0 += BK) {
        __syncthreads();
#pragma unroll
        for (int h2 = 0; h2 < 4; ++h2) {
            int c = t + h2 * 256;
            int r = c >> 3;
            int ko = (c & 7) * 8;
            int grow = row0 + r; if (grow >= n) grow = n - 1;
            *(uint4*)&As[r][ko] = *(const uint4*)(hcur + (size_t)grow * NDIM + k0 + ko);
        }
#pragma unroll
        for (int h2 = 0; h2 < 2; ++h2) {
            int c = t + h2 * 256;
            int r = c >> 3;
            int ko = (c & 7) * 8;
            size_t widx = (size_t)(n0 + r) * NDIM + k0 + ko;
            *(uint4*)&Bs[r][ko] = *(const uint4*)(WtB + widx);
            *(uint4*)&Cs[r][ko] = *(const uint4*)(WtC + widx);
        }
        __syncthreads();
#pragma unroll
        for (int ks = 0; ks < BK; ks += 32) {
            short8 af[4], bf[2], cf[2];
#pragma unroll
            for (int mt = 0; mt < 4; ++mt)
                af[mt] = *(const short8*)&As[wm * 64 + mt * 16 + l16][ks + quad * 8];
#pragma unroll
            for (int nt = 0; nt < 2; ++nt) {
                bf[nt] = *(const short8*)&Bs[wn * 32 + nt * 16 + l16][ks + quad * 8];
                cf[nt] = *(const short8*)&Cs[wn * 32 + nt * 16 + l16][ks + quad * 8];
            }
#pragma unroll
            for (int mt = 0; mt < 4; ++mt)
#pragma unroll
                for (int nt = 0; nt < 2; ++nt) {
                    acc1[mt][nt] = __builtin_amdgcn_mfma_f32_16x16x32_bf16(af[mt], bf[nt], acc1[mt][nt], 0, 0, 0);
                    acc2[mt][nt] = __builtin_amdgcn_mfma_f32_16x16x32_bf16(af[mt], cf[nt], acc2[mt][nt], 0, 0, 0);
                }
        }
    }
    // epilogue
#pragma unroll
    for (int mt = 0; mt < 4; ++mt) {
#pragma unroll
        for (int nt = 0; nt < 2; ++nt) {
            int lcol = wn * 32 + nt * 16 + l16;
            int col = n0 + lcol;
            float bu = bupd[col];
            float cv = cvec[col];
            float cmax = 0.f;
#pragma unroll
            for (int r = 0; r < 4; ++r) {
                int row = row0 + wm * 64 + mt * 16 + quad * 4 + r;
                if (row < n) {
                    float dg = (float)deg[row];
                    float v = fmaxf(acc1[mt][nt][r] + dg * (acc2[mt][nt][r] + cv) + bu, 0.f);
                    Out[(size_t)row * NDIM + col] = f2b(v);
                    if (!LAST) Out8[(size_t)row * NDIM + col] = f2fp8(v);
                    if (LAST) cmax = fmaxf(cmax, v);
                }
            }
            if (LAST) atomicMax(&smax[lcol], __float_as_int(cmax));
        }
    }
    if (LAST) {
        __syncthreads();
        if (t < BN) atomicMax(&geInt[n0 + t], smax[t]);
    }
}

// ---------- final ----------
__global__ __launch_bounds__(1024) void out_kernel(const float* __restrict__ ge,
                                                   const float* __restrict__ W_out,
                                                   const float* __restrict__ b_out,
                                                   float* __restrict__ out) {
    __shared__ float red[4][NDIM];
    int t = threadIdx.x & 255;
    int g = threadIdx.x >> 8;
    float acc = 0.f;
#pragma unroll 8
    for (int kk = 0; kk < 64; ++kk) {
        int k = g * 64 + kk;
        acc += ge[k] * W_out[k * NDIM + t];
    }
    red[g][t] = acc;
    __syncthreads();
    if (g == 0)
        out[t] = b_out[t] + red[0][t] + red[1][t] + red[2][t] + red[3][t];
}

// ---------- launch ----------
extern "C" void kernel_launch(void* const* d_in, const int* in_sizes, int n_in,
                              void* d_out, int out_size, void* d_ws, size_t ws_size,
                              hipStream_t stream) {
    const float* nodes      = (const float*)d_in[0];
    const int*   edges      = (const int*)d_in[1];
    const int*   node_types = (const int*)d_in[2];
    const float* type_emb   = (const float*)d_in[3];
    const float* W_proj     = (const float*)d_in[4];
    const float* b_proj     = (const float*)d_in[5];
    const float* W_msg      = (const float*)d_in[6];
    const float* b_msg      = (const float*)d_in[7];
    const float* W_upd      = (const float*)d_in[8];
    const float* b_upd      = (const float*)d_in[9];
    const float* W_out      = (const float*)d_in[10];
    const float* b_out      = (const float*)d_in[11];

    int n = in_sizes[2];
    int E = in_sizes[1] / 2;
    const int* src = edges;
    const int* dst = edges + E;

    size_t off = 0;
    auto alloc = [&](size_t bytes) {
        void* p = (char*)d_ws + off;
        off += (bytes + 255) & ~(size_t)255;
        return p;
    };
    int* deg    = (int*)alloc((size_t)(n + 4096) * 4);
    int* rowptr = (int*)alloc((size_t)(n + 1) * 4);
    int* cursor = (int*)alloc((size_t)n * 4);
    int* col    = (int*)alloc((size_t)(E + 8 * n) * 4);
    unsigned short* WtA = (unsigned short*)alloc((size_t)HOPS * 256 * 256 * 2);
    unsigned short* WtB = (unsigned short*)alloc((size_t)HOPS * 256 * 256 * 2);
    unsigned short* WtC = (unsigned short*)alloc((size_t)HOPS * 256 * 256 * 2);
    float* cvec = (float*)alloc((size_t)HOPS * 256 * 4);
    int* geInt  = (int*)alloc((size_t)256 * 4);
    unsigned short* hA  = (unsigned short*)alloc((size_t)(n + 1) * NDIM * 2);
    unsigned short* hB  = (unsigned short*)alloc((size_t)(n + 1) * NDIM * 2);
    unsigned short* Sb  = (unsigned short*)alloc((size_t)n * NDIM * 2);
    unsigned char* h8   = (unsigned char*)alloc((size_t)(n + 1) * NDIM);

    hipMemsetAsync(deg, 0, (size_t)(n + 4096) * 4, stream);
    int eb = (E + 255) / 256;
    int pb = (n + 255) / 256;
    prep_mega_kernel<<<eb + 389 + n, 256, 0, stream>>>(
        dst, deg, E, eb,
        W_msg, W_upd, b_msg, WtA, WtB, WtC, cvec, geInt, h8 + (size_t)n * NDIM,
        nodes, node_types, type_emb, W_proj, b_proj, hA, h8, n);
    scan_kernel<<<1, 1024, 0, stream>>>(deg, rowptr, cursor, n);
    fillpad_kernel<<<eb + pb, 256, 0, stream>>>(src, dst, cursor, rowptr, deg, col, E, eb, n);

    unsigned short* h  = hA;
    unsigned short* ho = hB;
    int gx = (n + BM - 1) / BM;
    dim3 ggrid(gx, NDIM / BN);
    for (int i = 0; i < HOPS; ++i) {
        agg_kernel<<<(n + 7) / 8, 256, 0, stream>>>(h8, rowptr, col, Sb, n);
        size_t wofs = (size_t)i * 256 * 256;
        if (i == HOPS - 1)
            gemm_hop_kernel<true><<<ggrid, 256, 0, stream>>>(
                Sb, h, deg, WtA + wofs, WtB + wofs, WtC + wofs,
                b_upd + (size_t)i * NDIM, cvec + (size_t)i * NDIM, ho, h8, geInt, n);
        else
            gemm_hop_kernel<false><<<ggrid, 256, 0, stream>>>(
                Sb, h, deg, WtA + wofs, WtB + wofs, WtC + wofs,
                b_upd + (size_t)i * NDIM, cvec + (size_t)i * NDIM, ho, h8, geInt, n);
        unsigned short* tmp = h; h = ho; ho = tmp;
    }
    out_kernel<<<1, 1024, 0, stream>>>((const float*)geInt, W_out, b_out, (float*)d_out);
}

// Round 24
// 364.919 us; speedup vs baseline: 1.5839x; 1.0432x over previous
//
#include <hip/hip_runtime.h>
#include <hip/hip_bf16.h>

#define NDIM 256
#define FDIM 32
#define HOPS 4
#define NPB 8   // nodes per init block

typedef __attribute__((ext_vector_type(8))) short short8;
typedef __attribute__((ext_vector_type(4))) float f32x4;
typedef __attribute__((ext_vector_type(2))) float f32x2;

// ---------- helpers ----------
__device__ inline float b2f(unsigned short u) {
    union { unsigned int i; float f; } v; v.i = ((unsigned int)u) << 16; return v.f;
}
__device__ inline unsigned short f2b(float f) {
    union { float f; unsigned int i; } v; v.f = f;
    unsigned int r = v.i + 0x7FFF + ((v.i >> 16) & 1);
    return (unsigned short)(r >> 16);
}
__device__ inline unsigned char f2fp8(float v) {
    return (unsigned char)(__builtin_amdgcn_cvt_pk_fp8_f32(v, v, 0, false) & 0xFF);
}

// ---------- prep mega: hist (0..histB-1) + wprep (histB..histB+388) + init_h batched (rest) ----------
__global__ __launch_bounds__(256) void prep_mega_kernel(
        const int* __restrict__ dst, int* __restrict__ deg, int E, int histB,
        const float* __restrict__ Wm, const float* __restrict__ Wu,
        const float* __restrict__ bm,
        unsigned short* __restrict__ WtA, unsigned short* __restrict__ WtB,
        unsigned short* __restrict__ WtC,
        float* __restrict__ cvec, int* __restrict__ geInt,
        unsigned char* __restrict__ h8row,
        const float* __restrict__ nodes, const int* __restrict__ node_types,
        const float* __restrict__ type_emb, const float* __restrict__ W_proj,
        const float* __restrict__ b_proj,
        unsigned short* __restrict__ h, unsigned char* __restrict__ h8, int n) {
    __shared__ float T[32][33];
    __shared__ float Af[32][68];
    __shared__ float Bf[32][68];
    __shared__ float sb[256];
    int b = blockIdx.x;
    int t = threadIdx.x;

    if (b < histB) {
        // ---- hist ----
        int e = b * 256 + t;
        if (e < E) atomicAdd(&deg[dst[e]], 1);
    } else if (b < histB + 389) {
        int bb = b - histB;
        if (bb < 256) {
            // ---- wtrans: WtB[hop][nn][k] = W_upd[hop][k][nn] ----
            int hop = bb >> 6;
            int rem = bb & 63;
            int k0 = (rem & 7) * 32, n0 = (rem >> 3) * 32;
            const float* src = Wu + (size_t)hop * 512 * 256;
            unsigned short* dstp = WtB + (size_t)hop * 256 * 256;
            int tr = t >> 5, tc = t & 31;
#pragma unroll
            for (int r = 0; r < 4; ++r) {
                int k = tr + r * 8;
                T[tc][k] = src[(size_t)(k0 + k) * 256 + n0 + tc];
            }
            __syncthreads();
#pragma unroll
            for (int r = 0; r < 4; ++r) {
                int nn = tr + r * 8;
                dstp[(size_t)(n0 + nn) * 256 + k0 + tc] = f2b(T[nn][tc]);
            }
        } else if (bb < 384) {
            // ---- mm: M = Wm_half @ Wu2, stored transposed ----
            int idx = bb - 256;
            int m = idx >> 4;
            int rem = idx & 15;
            int k0 = (rem & 3) * 64, n0 = (rem >> 2) * 64;
            int hop = m >> 1, which = m & 1;
            const float* A = Wm + (size_t)hop * 512 * 256 + (size_t)which * 256 * 256;
            const float* B = Wu + (size_t)hop * 512 * 256 + (size_t)256 * 256;
            unsigned short* W = (which ? WtC : WtA) + (size_t)hop * 256 * 256;
            int tx = t & 15, ty = t >> 4;
            float acc[4][4];
#pragma unroll
            for (int a = 0; a < 4; ++a)
#pragma unroll
                for (int c = 0; c < 4; ++c) acc[a][c] = 0.f;

            for (int j0 = 0; j0 < 256; j0 += 32) {
                __syncthreads();
#pragma unroll
                for (int c = 0; c < 2; ++c) {
                    int idx2 = t + c * 256;
                    int kk = idx2 >> 3;
                    int jj = (idx2 & 7) * 4;
                    float4 va = *(const float4*)&A[(size_t)(k0 + kk) * 256 + j0 + jj];
                    Af[jj + 0][kk] = va.x; Af[jj + 1][kk] = va.y;
                    Af[jj + 2][kk] = va.z; Af[jj + 3][kk] = va.w;
                    int jj2 = idx2 >> 4;
                    int nn = (idx2 & 15) * 4;
                    float4 vb = *(const float4*)&B[(size_t)(j0 + jj2) * 256 + n0 + nn];
                    *(float4*)&Bf[jj2][nn] = vb;
                }
                __syncthreads();
#pragma unroll
                for (int jj = 0; jj < 32; ++jj) {
                    float av[4];
#pragma unroll
                    for (int a = 0; a < 4; ++a) av[a] = Af[jj][ty * 4 + a];
                    float4 bv = *(const float4*)&Bf[jj][tx * 4];
#pragma unroll
                    for (int a = 0; a < 4; ++a) {
                        acc[a][0] += av[a] * bv.x; acc[a][1] += av[a] * bv.y;
                        acc[a][2] += av[a] * bv.z; acc[a][3] += av[a] * bv.w;
                    }
                }
            }
#pragma unroll
            for (int c = 0; c < 4; ++c) {
                int nn = n0 + tx * 4 + c;
                ushort4 o;
                o.x = f2b(acc[0][c]); o.y = f2b(acc[1][c]);
                o.z = f2b(acc[2][c]); o.w = f2b(acc[3][c]);
                *(ushort4*)&W[(size_t)nn * 256 + k0 + ty * 4] = o;
            }
        } else if (bb < 388) {
            // ---- cvec[hop] = b_msg[hop] @ Wu2[hop] ----
            int hop = bb - 384;
            sb[t] = bm[hop * 256 + t];
            __syncthreads();
            const float* B = Wu + (size_t)hop * 512 * 256 + (size_t)256 * 256;
            float acc = 0.f;
#pragma unroll 8
            for (int j = 0; j < 256; ++j) acc += sb[j] * B[(size_t)j * 256 + t];
            cvec[hop * 256 + t] = acc;
        } else {
            geInt[t] = 0;
            h8row[t] = 0;
        }
    } else {
        // ---- init_h, NPB nodes per block ----
        int v0 = (b - histB - 389) * NPB;
        // stage NPB node feature rows: sb[j*32 + f]
        {
            int j = t >> 5, f = t & 31;      // 256 threads = 8 x 32
            int v = v0 + j;
            sb[t] = (v < n) ? nodes[(size_t)v * FDIM + f] : 0.f;
        }
        __syncthreads();
        float acc[NPB];
#pragma unroll
        for (int j = 0; j < NPB; ++j) {
            int v = v0 + j;
            acc[j] = (v < n) ? (b_proj[t] + type_emb[(size_t)node_types[v] * NDIM + t]) : 0.f;
        }
#pragma unroll 4
        for (int k = 0; k < FDIM; ++k) {
            float wv = W_proj[(size_t)k * NDIM + t];
#pragma unroll
            for (int j = 0; j < NPB; ++j)
                acc[j] += sb[j * FDIM + k] * wv;
        }
#pragma unroll
        for (int j = 0; j < NPB; ++j) {
            int v = v0 + j;
            if (v < n) {
                h[(size_t)v * NDIM + t] = f2b(acc[j]);
                h8[(size_t)v * NDIM + t] = f2fp8(acc[j]);
            }
        }
    }
}

// 1024-thread scan over degree-PADDED (multiple of 8) counts, int4-batched.
__global__ __launch_bounds__(1024) void scan_kernel(const int* __restrict__ deg,
                                                    int* __restrict__ rowptr,
                                                    int* __restrict__ cursor, int n) {
    __shared__ int wsum[16];
    int t = threadIdx.x;
    int per4 = (n + 4095) >> 12;
    int base = t * per4 * 4;
    int4 v4[8];
#pragma unroll 8
    for (int j = 0; j < per4; ++j) {
        int4 d = *(const int4*)(deg + base + j * 4);
        d.x = (d.x + 7) & ~7; d.y = (d.y + 7) & ~7;
        d.z = (d.z + 7) & ~7; d.w = (d.w + 7) & ~7;
        v4[j] = d;
    }
    int s = 0;
#pragma unroll 8
    for (int j = 0; j < per4; ++j) s += v4[j].x + v4[j].y + v4[j].z + v4[j].w;

    int lane = t & 63, wid = t >> 6;
    int v = s;
#pragma unroll
    for (int d = 1; d < 64; d <<= 1) {
        int u = __shfl_up(v, d, 64);
        if (lane >= d) v += u;
    }
    if (lane == 63) wsum[wid] = v;
    __syncthreads();
    if (wid == 0) {
        int ws = (lane < 16) ? wsum[lane] : 0;
#pragma unroll
        for (int d = 1; d < 16; d <<= 1) {
            int u = __shfl_up(ws, d, 64);
            if (lane >= d) ws += u;
        }
        if (lane < 16) wsum[lane] = ws;
    }
    __syncthreads();
    int run = (wid > 0 ? wsum[wid - 1] : 0) + (v - s);
#pragma unroll 8
    for (int j = 0; j < per4; ++j) {
        int idx = base + j * 4;
        int4 o;
        o.x = run; run += v4[j].x;
        o.y = run; run += v4[j].y;
        o.z = run; run += v4[j].z;
        o.w = run; run += v4[j].w;
        if (idx + 3 < n) {
            *(int4*)(rowptr + idx) = o;
            *(int4*)(cursor + idx) = o;
        } else if (idx < n) {
            const int* op = (const int*)&o;
            for (int e = 0; e < 4 && idx + e < n; ++e) {
                rowptr[idx + e] = op[e];
                cursor[idx + e] = op[e];
            }
        }
    }
    if (t == 1023) rowptr[n] = run;
}

// ---------- fill (blocks 0..fillB-1) + pad (rest); disjoint col ranges ----------
__global__ void fillpad_kernel(const int* __restrict__ src, const int* __restrict__ dst,
                               int* __restrict__ cursor,
                               const int* __restrict__ rowptr, const int* __restrict__ deg,
                               int* __restrict__ col, int E, int fillB, int n) {
    int b = blockIdx.x;
    int t = threadIdx.x;
    if (b < fillB) {
        int e = b * 256 + t;
        if (e < E) {
            int d = dst[e];
            int p = atomicAdd(&cursor[d], 1);
            col[p] = src[e];
        }
    } else {
        int v = (b - fillB) * 256 + t;
        if (v < n) {
            int s = rowptr[v] + deg[v];
            int e0 = rowptr[v + 1];
            for (int i = s; i < e0; ++i) col[i] = n;
        }
    }
}

// ---------- neighbor sum: fp8 gather (256B rows), fp32 accumulate, bf16 out ----------
__global__ __launch_bounds__(256) void agg_kernel(const unsigned char* __restrict__ h8,
                                                  const int* __restrict__ rowptr,
                                                  const int* __restrict__ col,
                                                  unsigned short* __restrict__ S, int n) {
    int wave = threadIdx.x >> 6;
    int lane = threadIdx.x & 63;
    int half = lane >> 5;
    int hl = lane & 31;
    int v = blockIdx.x * 8 + wave * 2 + half;
    if (v >= n) return;
    int beg = rowptr[v], end = rowptr[v + 1];
    float a[8];
#pragma unroll
    for (int e = 0; e < 8; ++e) a[e] = 0.f;
    int cofs = hl * 8;
    for (int i = beg; i < end; i += 8) {
        int cc[8];
#pragma unroll
        for (int j = 0; j < 8; ++j) cc[j] = col[i + j];
        uint2 x[8];
#pragma unroll
        for (int j = 0; j < 8; ++j)
            x[j] = *(const uint2*)(h8 + (size_t)cc[j] * NDIM + cofs);
#pragma unroll
        for (int j = 0; j < 8; ++j) {
            f32x2 p0 = __builtin_amdgcn_cvt_pk_f32_fp8(x[j].x, false);
            f32x2 p1 = __builtin_amdgcn_cvt_pk_f32_fp8(x[j].x, true);
            f32x2 p2 = __builtin_amdgcn_cvt_pk_f32_fp8(x[j].y, false);
            f32x2 p3 = __builtin_amdgcn_cvt_pk_f32_fp8(x[j].y, true);
            a[0] += p0[0]; a[1] += p0[1]; a[2] += p1[0]; a[3] += p1[1];
            a[4] += p2[0]; a[5] += p2[1]; a[6] += p3[0]; a[7] += p3[1];
        }
    }
    uint4 o;
    unsigned short* op = (unsigned short*)&o;
#pragma unroll
    for (int e = 0; e < 8; ++e) op[e] = f2b(a[e]);
    *(uint4*)&S[(size_t)v * NDIM + cofs] = o;
}

// ---------- fused hop GEMM: BM=128 BN=64 BK=64 two-phase dual-acc (R20 config) ----------
#define BM 128
#define BN 64
#define BK 64
#define ASTR (BK + 8)

template <bool LAST>
__global__ __launch_bounds__(256) void gemm_hop_kernel(const unsigned short* __restrict__ S,
                                                       const unsigned short* __restrict__ hcur,
                                                       const int* __restrict__ deg,
                                                       const unsigned short* __restrict__ WtA,
                                                       const unsigned short* __restrict__ WtB,
                                                       const unsigned short* __restrict__ WtC,
                                                       const float* __restrict__ bupd,
                                                       const float* __restrict__ cvec,
                                                       unsigned short* __restrict__ Out,
                                                       unsigned char* __restrict__ Out8,
                                                       int* __restrict__ geInt, int n) {
    __shared__ unsigned short As[BM][ASTR];
    __shared__ unsigned short Bs[BN][ASTR];
    __shared__ unsigned short Cs[BN][ASTR];
    __shared__ int smax[BN];
    int t = threadIdx.x;
    int lane = t & 63;
    int w = t >> 6;
    int wm = w >> 1, wn = w & 1;
    int quad = lane >> 4, l16 = lane & 15;
    int row0 = blockIdx.x * BM;
    int n0 = blockIdx.y * BN;

    if (LAST) {
        if (t < BN) smax[t] = 0;
    }

    f32x4 acc1[4][2], acc2[4][2];
#pragma unroll
    for (int i = 0; i < 4; ++i)
#pragma unroll
        for (int j = 0; j < 2; ++j) { acc1[i][j] = (f32x4)(0.f); acc2[i][j] = (f32x4)(0.f); }

    // phase 1: acc1 += S @ M1^T
    for (int k0 = 0; k0 < NDIM; k0 += BK) {
        __syncthreads();
#pragma unroll
        for (int h2 = 0; h2 < 4; ++h2) {
            int c = t + h2 * 256;
            int r = c >> 3;
            int ko = (c & 7) * 8;
            int grow = row0 + r; if (grow >= n) grow = n - 1;
            *(uint4*)&As[r][ko] = *(const uint4*)(S + (size_t)grow * NDIM + k0 + ko);
        }
#pragma unroll
        for (int h2 = 0; h2 < 2; ++h2) {
            int c = t + h2 * 256;
            int r = c >> 3;
            int ko = (c & 7) * 8;
            *(uint4*)&Bs[r][ko] = *(const uint4*)(WtA + (size_t)(n0 + r) * NDIM + k0 + ko);
        }
        __syncthreads();
#pragma unroll
        for (int ks = 0; ks < BK; ks += 32) {
            short8 af[4], bf[2];
#pragma unroll
            for (int mt = 0; mt < 4; ++mt)
                af[mt] = *(const short8*)&As[wm * 64 + mt * 16 + l16][ks + quad * 8];
#pragma unroll
            for (int nt = 0; nt < 2; ++nt)
                bf[nt] = *(const short8*)&Bs[wn * 32 + nt * 16 + l16][ks + quad * 8];
#pragma unroll
            for (int mt = 0; mt < 4; ++mt)
#pragma unroll
                for (int nt = 0; nt < 2; ++nt)
                    acc1[mt][nt] = __builtin_amdgcn_mfma_f32_16x16x32_bf16(af[mt], bf[nt], acc1[mt][nt], 0, 0, 0);
        }
    }
    // phase 2: acc1 += h @ Wu1^T ; acc2 += h @ M2^T
    for (int k0 = 0; k0 < NDIM; k0 += BK) {
        __syncthreads();
#pragma unroll
        for (int h2 = 0; h2 < 4; ++h2) {
            int c = t + h2 * 256;
            int r = c >> 3;
            int ko = (c & 7) * 8;
            int grow = row0 + r; if (grow >= n) grow = n - 1;
            *(uint4*)&As[r][ko] = *(const uint4*)(hcur + (size_t)grow * NDIM + k0 + ko);
        }
#pragma unroll
        for (int h2 = 0; h2 < 2; ++h2) {
            int c = t + h2 * 256;
            int r = c >> 3;
            int ko = (c & 7) * 8;
            size_t widx = (size_t)(n0 + r) * NDIM + k0 + ko;
            *(uint4*)&Bs[r][ko] = *(const uint4*)(WtB + widx);
            *(uint4*)&Cs[r][ko] = *(const uint4*)(WtC + widx);
        }
        __syncthreads();
#pragma unroll
        for (int ks = 0; ks < BK; ks += 32) {
            short8 af[4], bf[2], cf[2];
#pragma unroll
            for (int mt = 0; mt < 4; ++mt)
                af[mt] = *(const short8*)&As[wm * 64 + mt * 16 + l16][ks + quad * 8];
#pragma unroll
            for (int nt = 0; nt < 2; ++nt) {
                bf[nt] = *(const short8*)&Bs[wn * 32 + nt * 16 + l16][ks + quad * 8];
                cf[nt] = *(const short8*)&Cs[wn * 32 + nt * 16 + l16][ks + quad * 8];
            }
#pragma unroll
            for (int mt = 0; mt < 4; ++mt)
#pragma unroll
                for (int nt = 0; nt < 2; ++nt) {
                    acc1[mt][nt] = __builtin_amdgcn_mfma_f32_16x16x32_bf16(af[mt], bf[nt], acc1[mt][nt], 0, 0, 0);
                    acc2[mt][nt] = __builtin_amdgcn_mfma_f32_16x16x32_bf16(af[mt], cf[nt], acc2[mt][nt], 0, 0, 0);
                }
        }
    }
    // epilogue
#pragma unroll
    for (int mt = 0; mt < 4; ++mt) {
#pragma unroll
        for (int nt = 0; nt < 2; ++nt) {
            int lcol = wn * 32 + nt * 16 + l16;
            int col = n0 + lcol;
            float bu = bupd[col];
            float cv = cvec[col];
            float cmax = 0.f;
#pragma unroll
            for (int r = 0; r < 4; ++r) {
                int row = row0 + wm * 64 + mt * 16 + quad * 4 + r;
                if (row < n) {
                    float dg = (float)deg[row];
                    float v = fmaxf(acc1[mt][nt][r] + dg * (acc2[mt][nt][r] + cv) + bu, 0.f);
                    Out[(size_t)row * NDIM + col] = f2b(v);
                    if (!LAST) Out8[(size_t)row * NDIM + col] = f2fp8(v);
                    if (LAST) cmax = fmaxf(cmax, v);
                }
            }
            if (LAST) atomicMax(&smax[lcol], __float_as_int(cmax));
        }
    }
    if (LAST) {
        __syncthreads();
        if (t < BN) atomicMax(&geInt[n0 + t], smax[t]);
    }
}

// ---------- final ----------
__global__ __launch_bounds__(1024) void out_kernel(const float* __restrict__ ge,
                                                   const float* __restrict__ W_out,
                                                   const float* __restrict__ b_out,
                                                   float* __restrict__ out) {
    __shared__ float red[4][NDIM];
    int t = threadIdx.x & 255;
    int g = threadIdx.x >> 8;
    float acc = 0.f;
#pragma unroll 8
    for (int kk = 0; kk < 64; ++kk) {
        int k = g * 64 + kk;
        acc += ge[k] * W_out[k * NDIM + t];
    }
    red[g][t] = acc;
    __syncthreads();
    if (g == 0)
        out[t] = b_out[t] + red[0][t] + red[1][t] + red[2][t] + red[3][t];
}

// ---------- launch ----------
extern "C" void kernel_launch(void* const* d_in, const int* in_sizes, int n_in,
                              void* d_out, int out_size, void* d_ws, size_t ws_size,
                              hipStream_t stream) {
    const float* nodes      = (const float*)d_in[0];
    const int*   edges      = (const int*)d_in[1];
    const int*   node_types = (const int*)d_in[2];
    const float* type_emb   = (const float*)d_in[3];
    const float* W_proj     = (const float*)d_in[4];
    const float* b_proj     = (const float*)d_in[5];
    const float* W_msg      = (const float*)d_in[6];
    const float* b_msg      = (const float*)d_in[7];
    const float* W_upd      = (const float*)d_in[8];
    const float* b_upd      = (const float*)d_in[9];
    const float* W_out      = (const float*)d_in[10];
    const float* b_out      = (const float*)d_in[11];

    int n = in_sizes[2];
    int E = in_sizes[1] / 2;
    const int* src = edges;
    const int* dst = edges + E;

    size_t off = 0;
    auto alloc = [&](size_t bytes) {
        void* p = (char*)d_ws + off;
        off += (bytes + 255) & ~(size_t)255;
        return p;
    };
    int* deg    = (int*)alloc((size_t)(n + 4096) * 4);
    int* rowptr = (int*)alloc((size_t)(n + 1) * 4);
    int* cursor = (int*)alloc((size_t)n * 4);
    int* col    = (int*)alloc((size_t)(E + 8 * n) * 4);
    unsigned short* WtA = (unsigned short*)alloc((size_t)HOPS * 256 * 256 * 2);
    unsigned short* WtB = (unsigned short*)alloc((size_t)HOPS * 256 * 256 * 2);
    unsigned short* WtC = (unsigned short*)alloc((size_t)HOPS * 256 * 256 * 2);
    float* cvec = (float*)alloc((size_t)HOPS * 256 * 4);
    int* geInt  = (int*)alloc((size_t)256 * 4);
    unsigned short* hA  = (unsigned short*)alloc((size_t)(n + 1) * NDIM * 2);
    unsigned short* hB  = (unsigned short*)alloc((size_t)(n + 1) * NDIM * 2);
    unsigned short* Sb  = (unsigned short*)alloc((size_t)n * NDIM * 2);
    unsigned char* h8   = (unsigned char*)alloc((size_t)(n + 1) * NDIM);

    hipMemsetAsync(deg, 0, (size_t)(n + 4096) * 4, stream);
    int eb = (E + 255) / 256;
    int pb = (n + 255) / 256;
    int ib = (n + NPB - 1) / NPB;
    prep_mega_kernel<<<eb + 389 + ib, 256, 0, stream>>>(
        dst, deg, E, eb,
        W_msg, W_upd, b_msg, WtA, WtB, WtC, cvec, geInt, h8 + (size_t)n * NDIM,
        nodes, node_types, type_emb, W_proj, b_proj, hA, h8, n);
    scan_kernel<<<1, 1024, 0, stream>>>(deg, rowptr, cursor, n);
    fillpad_kernel<<<eb + pb, 256, 0, stream>>>(src, dst, cursor, rowptr, deg, col, E, eb, n);

    unsigned short* h  = hA;
    unsigned short* ho = hB;
    int gx = (n + BM - 1) / BM;
    dim3 ggrid(gx, NDIM / BN);
    for (int i = 0; i < HOPS; ++i) {
        agg_kernel<<<(n + 7) / 8, 256, 0, stream>>>(h8, rowptr, col, Sb, n);
        size_t wofs = (size_t)i * 256 * 256;
        if (i == HOPS - 1)
            gemm_hop_kernel<true><<<ggrid, 256, 0, stream>>>(
                Sb, h, deg, WtA + wofs, WtB + wofs, WtC + wofs,
                b_upd + (size_t)i * NDIM, cvec + (size_t)i * NDIM, ho, h8, geInt, n);
        else
            gemm_hop_kernel<false><<<ggrid, 256, 0, stream>>>(
                Sb, h, deg, WtA + wofs, WtB + wofs, WtC + wofs,
                b_upd + (size_t)i * NDIM, cvec + (size_t)i * NDIM, ho, h8, geInt, n);
        unsigned short* tmp = h; h = ho; ho = tmp;
    }
    out_kernel<<<1, 1024, 0, stream>>>((const float*)geInt, W_out, b_out, (float*)d_out);
}